// Round 8
// baseline (96.703 us; speedup 1.0000x reference)
//
#include <hip/hip_runtime.h>

#define MAX_RIGID 8

// X,Y,O are 4x3 affine: [0..8] rot row-major, [9..11] translation
__device__ __forceinline__ void combine12(const float* X, const float* Y, float* O) {
    #pragma unroll
    for (int i = 0; i < 3; ++i) {
        #pragma unroll
        for (int k = 0; k < 3; ++k)
            O[i*3+k] = X[i*3+0]*Y[0+k] + X[i*3+1]*Y[3+k] + X[i*3+2]*Y[6+k];
        O[9+i] = X[i*3+0]*Y[9] + X[i*3+1]*Y[10] + X[i*3+2]*Y[11] + X[9+i];
    }
}

// Tables in LDS (stride-100 padding, validated R7). NEW: per-lane opr spill
// buffer in LDS, layout [wave][rigid*12+comp][lane] so the divergent 1-of-8
// gather is a conflict-free lane-local ds_read (addr%32 == lane%32 for any g).
// Buffer is lane-private: no barriers needed for it.
__global__ __launch_bounds__(256) void build_struct_kernel(
    const float* __restrict__ out0,   // [N,14]
    const float* __restrict__ out1,   // [N,9]
    const float* __restrict__ pos,    // [N,3]
    const float* __restrict__ rigidT, // [22,8,12]
    const float* __restrict__ rigidG, // [22,24,3]
    const int*   __restrict__ resty,  // [N]
    const int*   __restrict__ tdep,   // [22,8]
    const int*   __restrict__ gdep,   // [22,24]
    const int*   __restrict__ nrp,
    float* __restrict__ dR,           // [N,72]
    float* __restrict__ dOprBB,       // [N,12]
    float* __restrict__ dBB,          // [N,12]
    float* __restrict__ dSC,          // [N,14]
    int N)
{
    __shared__ float sT[2200];        // [22][100]
    __shared__ float sG[2200];        // [22][100], atom a at +a*4
    __shared__ int   sgd[616];        // [22][28]
    __shared__ int   stdp[264];       // [22][12]
    __shared__ float sbuf[4][96][64]; // 96 KB: per-wave, per-lane opr store

    const int tid  = threadIdx.x;
    const int lane = tid & 63;
    const int w    = tid >> 6;

    // ---- table staging (one-time, coalesced) ----
    for (int i = tid; i < 2112; i += 256) { int r = i / 96;  sT[r*100 + (i - r*96)] = rigidT[i]; }
    for (int i = tid; i < 1584; i += 256) { int r = i / 72;  int q = i - r*72; int a = q / 3;
                                            sG[r*100 + a*4 + (q - a*3)] = rigidG[i]; }
    for (int i = tid; i < 528;  i += 256) { int r = i / 24;  sgd[r*28 + (i - r*24)] = gdep[i]; }
    for (int i = tid; i < 176;  i += 256) { int r = i >> 3;  stdp[r*12 + (i & 7)]   = tdep[i]; }
    __syncthreads();   // only barrier in the kernel

    long n = (long)blockIdx.x * 256 + tid;
    if (n >= N) return;

    int iv = *nrp;
    float nrv = (iv > 0 && iv < 1000000) ? (float)iv
                                         : *reinterpret_cast<const float*>(nrp);
    float tscale = 0.1f / nrv;

    // ---- per-lane input loads ----
    float o0r[14];
    {
        const float2* p = reinterpret_cast<const float2*>(out0 + (size_t)n * 14);
        #pragma unroll
        for (int k = 0; k < 7; ++k) { float2 v = p[k]; o0r[2*k] = v.x; o0r[2*k+1] = v.y; }
    }
    float o1r[9];
    {
        const float* p = out1 + (size_t)n * 9;
        #pragma unroll
        for (int k = 0; k < 9; ++k) o1r[k] = p[k];
    }
    float px = pos[(size_t)n*3+0], py = pos[(size_t)n*3+1], pz = pos[(size_t)n*3+2];
    int rt = resty[n];

    // ---- sc ----
    float sc[14];
    #pragma unroll
    for (int k = 0; k < 7; ++k) {
        float a = o0r[2*k], b = o0r[2*k+1];
        float r = __builtin_amdgcn_rsqf(a*a + b*b + 1e-12f);
        sc[2*k] = a*r; sc[2*k+1] = b*r;
    }
    // ---- bb ----
    float bb[12];
    {
        float v0x=o1r[0], v0y=o1r[1], v0z=o1r[2];
        float v1x=o1r[3], v1y=o1r[4], v1z=o1r[5];
        float r0 = __builtin_amdgcn_rsqf(v0x*v0x + v0y*v0y + v0z*v0z + 1e-12f);
        float e0x=v0x*r0, e0y=v0y*r0, e0z=v0z*r0;
        float dp = e0x*v1x + e0y*v1y + e0z*v1z;
        float u1x = v1x - e0x*dp, u1y = v1y - e0y*dp, u1z = v1z - e0z*dp;
        float r1 = __builtin_amdgcn_rsqf(u1x*u1x + u1y*u1y + u1z*u1z + 1e-12f);
        float e1x=u1x*r1, e1y=u1y*r1, e1z=u1z*r1;
        float e2x = e0y*e1z - e0z*e1y;
        float e2y = e0z*e1x - e0x*e1z;
        float e2z = e0x*e1y - e0y*e1x;
        bb[0]=e0x; bb[1]=e1x; bb[2]=e2x;
        bb[3]=e0y; bb[4]=e1y; bb[5]=e2y;
        bb[6]=e0z; bb[7]=e1z; bb[8]=e2z;
        bb[9]=tscale*o1r[6]; bb[10]=tscale*o1r[7]; bb[11]=tscale*o1r[8];
    }

    // ---- table gathers from LDS (padded strides) ----
    const float4* T4 = reinterpret_cast<const float4*>(sT + rt * 100);
    int tdr[8];
    {
        const int4* t4 = reinterpret_cast<const int4*>(stdp + rt * 12);
        int4 a = t4[0], b = t4[1];
        tdr[0]=a.x; tdr[1]=a.y; tdr[2]=a.z; tdr[3]=a.w;
        tdr[4]=b.x; tdr[5]=b.y; tdr[6]=b.z; tdr[7]=b.w;
    }

    // ---- rigid chain (register copy for the sequential deps) + LDS spill ----
    float opr[MAX_RIGID][12];
    {
        float X[12];
        { float4 r0v=T4[0], r1v=T4[1], r2v=T4[2];
          X[0]=r0v.x; X[1]=r0v.y; X[2]=r0v.z; X[3]=r0v.w;
          X[4]=r1v.x; X[5]=r1v.y; X[6]=r1v.z; X[7]=r1v.w;
          X[8]=r2v.x; X[9]=r2v.y; X[10]=r2v.z; X[11]=r2v.w; }
        float Y[12] = { bb[0],bb[1],bb[2], bb[3],bb[4],bb[5], bb[6],bb[7],bb[8],
                        bb[9]+px, bb[10]+py, bb[11]+pz };
        combine12(X, Y, opr[0]);
        #pragma unroll
        for (int j = 0; j < 12; ++j) sbuf[w][j][lane] = opr[0][j];
    }
    #pragma unroll
    for (int i = 1; i < MAX_RIGID; ++i) {
        float X[12];
        { float4 r0v=T4[i*3], r1v=T4[i*3+1], r2v=T4[i*3+2];
          X[0]=r0v.x; X[1]=r0v.y; X[2]=r0v.z; X[3]=r0v.w;
          X[4]=r1v.x; X[5]=r1v.y; X[6]=r1v.z; X[7]=r1v.w;
          X[8]=r2v.x; X[9]=r2v.y; X[10]=r2v.z; X[11]=r2v.w; }
        float c = sc[2*(i-1)], s = sc[2*(i-1)+1];
        float M[12];
        M[0]=X[0]; M[3]=X[3]; M[6]=X[6];
        M[1] = c*X[1] + s*X[2];   M[2] = c*X[2] - s*X[1];
        M[4] = c*X[4] + s*X[5];   M[5] = c*X[5] - s*X[4];
        M[7] = c*X[7] + s*X[8];   M[8] = c*X[8] - s*X[7];
        M[9]=X[9]; M[10]=X[10]; M[11]=X[11];
        int t = tdr[i];
        float P[12];
        #pragma unroll
        for (int j = 0; j < 12; ++j) P[j] = opr[0][j];
        #pragma unroll
        for (int cnd = 1; cnd < i; ++cnd) {
            bool take = (t == cnd);
            #pragma unroll
            for (int j = 0; j < 12; ++j) P[j] = take ? opr[cnd][j] : P[j];
        }
        combine12(P, M, opr[i]);
        #pragma unroll
        for (int j = 0; j < 12; ++j) sbuf[w][i*12 + j][lane] = opr[i][j];
    }

    // ---- small outputs: direct vectorized stores ----
    {
        float2* d0 = reinterpret_cast<float2*>(dSC + (size_t)n * 14);
        #pragma unroll
        for (int k = 0; k < 7; ++k) d0[k] = make_float2(sc[2*k], sc[2*k+1]);
        float4* d1 = reinterpret_cast<float4*>(dBB + (size_t)n * 12);
        #pragma unroll
        for (int k = 0; k < 3; ++k) d1[k] = make_float4(bb[4*k], bb[4*k+1], bb[4*k+2], bb[4*k+3]);
        float4* d2 = reinterpret_cast<float4*>(dOprBB + (size_t)n * 12);
        #pragma unroll
        for (int k = 0; k < 3; ++k) d2[k] = make_float4(opr[0][4*k], opr[0][4*k+1], opr[0][4*k+2], opr[0][4*k+3]);
    }

    // ---- atoms: gather transform from LDS (conflict-free lane column) ----
    const float4* G4  = reinterpret_cast<const float4*>(sG + rt * 100);
    const int4*   gd4 = reinterpret_cast<const int4*>(sgd + rt * 28);
    float* Rout = dR + (size_t)n * 72;
    #pragma unroll
    for (int c = 0; c < 3; ++c) {
        int4 ga = gd4[c*2], gb = gd4[c*2+1];
        int gch[8] = {ga.x, ga.y, ga.z, ga.w, gb.x, gb.y, gb.z, gb.w};
        float rbuf[24];
        #pragma unroll
        for (int a4 = 0; a4 < 8; ++a4) {
            int a = c*8 + a4;
            float4 gv = G4[a];
            int gb12 = gch[a4] * 12;
            float O[12];
            #pragma unroll
            for (int j = 0; j < 12; ++j) O[j] = sbuf[w][gb12 + j][lane];
            rbuf[a4*3+0] = O[0]*gv.x + O[1]*gv.y + O[2]*gv.z + O[9];
            rbuf[a4*3+1] = O[3]*gv.x + O[4]*gv.y + O[5]*gv.z + O[10];
            rbuf[a4*3+2] = O[6]*gv.x + O[7]*gv.y + O[8]*gv.z + O[11];
        }
        float4* dst = reinterpret_cast<float4*>(Rout + c * 24);
        #pragma unroll
        for (int q = 0; q < 6; ++q)
            dst[q] = make_float4(rbuf[4*q], rbuf[4*q+1], rbuf[4*q+2], rbuf[4*q+3]);
    }
}

extern "C" void kernel_launch(void* const* d_in, const int* in_sizes, int n_in,
                              void* d_out, int out_size, void* d_ws, size_t ws_size,
                              hipStream_t stream) {
    const float* out0 = (const float*)d_in[0];
    const float* out1 = (const float*)d_in[1];
    const float* pos  = (const float*)d_in[2];
    const float* rT   = (const float*)d_in[3];
    const float* rG   = (const float*)d_in[4];
    const int*   res  = (const int*)d_in[5];
    const int*   td   = (const int*)d_in[6];
    const int*   gd   = (const int*)d_in[7];
    const int*   nr   = (const int*)d_in[8];

    int N = in_sizes[5];

    float* dR     = (float*)d_out;
    float* dOprBB = dR + (size_t)N * 72;
    float* dBB    = dOprBB + (size_t)N * 12;
    float* dSC    = dBB + (size_t)N * 12;

    dim3 grid((N + 255) / 256), block(256);
    hipLaunchKernelGGL(build_struct_kernel, grid, block, 0, stream,
                       out0, out1, pos, rT, rG, res, td, gd, nr,
                       dR, dOprBB, dBB, dSC, N);
}

// Round 9
// 74.570 us; speedup vs baseline: 1.2968x; 1.2968x over previous
//
#include <hip/hip_runtime.h>

#define MAX_RIGID 8

// fp16x2 pack/unpack (pkrtz: round-toward-zero, <=1ulp)
__device__ __forceinline__ unsigned pkh(float a, float b) {
    return __builtin_bit_cast(unsigned, __builtin_amdgcn_cvt_pkrtz(a, b));
}
__device__ __forceinline__ float uplo(unsigned u) {
    return (float)__builtin_bit_cast(_Float16, (unsigned short)(u & 0xffffu));
}
__device__ __forceinline__ float uphi(unsigned u) {
    return (float)__builtin_bit_cast(_Float16, (unsigned short)(u >> 16));
}

// X,Y,O are 4x3 affine: [0..8] rot row-major, [9..11] translation
__device__ __forceinline__ void combine12(const float* X, const float* Y, float* O) {
    #pragma unroll
    for (int i = 0; i < 3; ++i) {
        #pragma unroll
        for (int k = 0; k < 3; ++k)
            O[i*3+k] = X[i*3+0]*Y[0+k] + X[i*3+1]*Y[3+k] + X[i*3+2]*Y[6+k];
        O[9+i] = X[i*3+0]*Y[9] + X[i*3+1]*Y[10] + X[i*3+2]*Y[11] + X[9+i];
    }
}

// LDS budget (52.2 KB -> 3 blocks/CU):
//   sG   [22][100] f32 table (stride-100 padding, validated R7)   8.8 KB
//   sgdp [22][4]   nibble-packed gdep                             0.35 KB
//   stdp [22]      nibble-packed tdep                             0.09 KB
//   sbh  [4][42][64] fp16x2 opr[1..7] per lane (lane-private)    43.0 KB
// opr[0] stays in f32 registers (exact for dOprBB; merged when g==0).
// T table read from global (16B-aligned f4, L1-resident).
__global__ __launch_bounds__(256) void build_struct_kernel(
    const float* __restrict__ out0,   // [N,14]
    const float* __restrict__ out1,   // [N,9]
    const float* __restrict__ pos,    // [N,3]
    const float* __restrict__ rigidT, // [22,8,12]
    const float* __restrict__ rigidG, // [22,24,3]
    const int*   __restrict__ resty,  // [N]
    const int*   __restrict__ tdep,   // [22,8]
    const int*   __restrict__ gdep,   // [22,24]
    const int*   __restrict__ nrp,
    float* __restrict__ dR,           // [N,72]
    float* __restrict__ dOprBB,       // [N,12]
    float* __restrict__ dBB,          // [N,12]
    float* __restrict__ dSC,          // [N,14]
    int N)
{
    __shared__ float    sG[2200];
    __shared__ unsigned sgdp[88];
    __shared__ unsigned stdp[22];
    __shared__ unsigned sbh[4][42][64];

    const int tid  = threadIdx.x;
    const int lane = tid & 63;
    const int w    = tid >> 6;

    // ---- staging (coalesced / tiny) ----
    for (int i = tid; i < 1584; i += 256) { int r = i / 72; int q = i - r*72; int a = q / 3;
                                            sG[r*100 + a*4 + (q - a*3)] = rigidG[i]; }
    if (tid < 22) {
        unsigned p0 = 0, p1 = 0, p2 = 0, tw = 0;
        #pragma unroll
        for (int a = 0; a < 8; ++a) {
            p0 |= ((unsigned)gdep[tid*24 +      a] & 7u) << (a*4);
            p1 |= ((unsigned)gdep[tid*24 +  8 + a] & 7u) << (a*4);
            p2 |= ((unsigned)gdep[tid*24 + 16 + a] & 7u) << (a*4);
            tw |= ((unsigned)tdep[tid*8  +      a] & 7u) << (a*4);
        }
        sgdp[tid*4+0] = p0; sgdp[tid*4+1] = p1; sgdp[tid*4+2] = p2;
        stdp[tid] = tw;
    }
    __syncthreads();   // only barrier in the kernel

    long n = (long)blockIdx.x * 256 + tid;
    if (n >= N) return;

    int iv = *nrp;
    float nrv = (iv > 0 && iv < 1000000) ? (float)iv
                                         : *reinterpret_cast<const float*>(nrp);
    float tscale = 0.1f / nrv;

    // ---- per-lane input loads ----
    float o0r[14];
    {
        const float2* p = reinterpret_cast<const float2*>(out0 + (size_t)n * 14);
        #pragma unroll
        for (int k = 0; k < 7; ++k) { float2 v = p[k]; o0r[2*k] = v.x; o0r[2*k+1] = v.y; }
    }
    float o1r[9];
    {
        const float* p = out1 + (size_t)n * 9;
        #pragma unroll
        for (int k = 0; k < 9; ++k) o1r[k] = p[k];
    }
    float px = pos[(size_t)n*3+0], py = pos[(size_t)n*3+1], pz = pos[(size_t)n*3+2];
    int rt = resty[n];

    // ---- sc ----
    float sc[14];
    #pragma unroll
    for (int k = 0; k < 7; ++k) {
        float a = o0r[2*k], b = o0r[2*k+1];
        float r = __builtin_amdgcn_rsqf(a*a + b*b + 1e-12f);
        sc[2*k] = a*r; sc[2*k+1] = b*r;
    }
    // ---- bb ----
    float bb[12];
    {
        float v0x=o1r[0], v0y=o1r[1], v0z=o1r[2];
        float v1x=o1r[3], v1y=o1r[4], v1z=o1r[5];
        float r0 = __builtin_amdgcn_rsqf(v0x*v0x + v0y*v0y + v0z*v0z + 1e-12f);
        float e0x=v0x*r0, e0y=v0y*r0, e0z=v0z*r0;
        float dp = e0x*v1x + e0y*v1y + e0z*v1z;
        float u1x = v1x - e0x*dp, u1y = v1y - e0y*dp, u1z = v1z - e0z*dp;
        float r1 = __builtin_amdgcn_rsqf(u1x*u1x + u1y*u1y + u1z*u1z + 1e-12f);
        float e1x=u1x*r1, e1y=u1y*r1, e1z=u1z*r1;
        float e2x = e0y*e1z - e0z*e1y;
        float e2y = e0z*e1x - e0x*e1z;
        float e2z = e0x*e1y - e0y*e1x;
        bb[0]=e0x; bb[1]=e1x; bb[2]=e2x;
        bb[3]=e0y; bb[4]=e1y; bb[5]=e2y;
        bb[6]=e0z; bb[7]=e1z; bb[8]=e2z;
        bb[9]=tscale*o1r[6]; bb[10]=tscale*o1r[7]; bb[11]=tscale*o1r[8];
    }

    // ---- per-type metadata ----
    const float4* T4 = reinterpret_cast<const float4*>(rigidT + rt * 96);  // global, L1
    unsigned tw  = stdp[rt];
    unsigned gw0 = sgdp[rt*4+0], gw1 = sgdp[rt*4+1], gw2 = sgdp[rt*4+2];

    // ---- rigid chain (f32 registers, select chain as R7) + fp16 spill ----
    float opr[MAX_RIGID][12];
    {
        float X[12];
        { float4 r0v=T4[0], r1v=T4[1], r2v=T4[2];
          X[0]=r0v.x; X[1]=r0v.y; X[2]=r0v.z; X[3]=r0v.w;
          X[4]=r1v.x; X[5]=r1v.y; X[6]=r1v.z; X[7]=r1v.w;
          X[8]=r2v.x; X[9]=r2v.y; X[10]=r2v.z; X[11]=r2v.w; }
        float Y[12] = { bb[0],bb[1],bb[2], bb[3],bb[4],bb[5], bb[6],bb[7],bb[8],
                        bb[9]+px, bb[10]+py, bb[11]+pz };
        combine12(X, Y, opr[0]);
    }
    #pragma unroll
    for (int i = 1; i < MAX_RIGID; ++i) {
        float X[12];
        { float4 r0v=T4[i*3], r1v=T4[i*3+1], r2v=T4[i*3+2];
          X[0]=r0v.x; X[1]=r0v.y; X[2]=r0v.z; X[3]=r0v.w;
          X[4]=r1v.x; X[5]=r1v.y; X[6]=r1v.z; X[7]=r1v.w;
          X[8]=r2v.x; X[9]=r2v.y; X[10]=r2v.z; X[11]=r2v.w; }
        float c = sc[2*(i-1)], s = sc[2*(i-1)+1];
        float M[12];
        M[0]=X[0]; M[3]=X[3]; M[6]=X[6];
        M[1] = c*X[1] + s*X[2];   M[2] = c*X[2] - s*X[1];
        M[4] = c*X[4] + s*X[5];   M[5] = c*X[5] - s*X[4];
        M[7] = c*X[7] + s*X[8];   M[8] = c*X[8] - s*X[7];
        M[9]=X[9]; M[10]=X[10]; M[11]=X[11];
        int t = (int)((tw >> (i*4)) & 7u);
        float P[12];
        #pragma unroll
        for (int j = 0; j < 12; ++j) P[j] = opr[0][j];
        #pragma unroll
        for (int cnd = 1; cnd < i; ++cnd) {
            bool take = (t == cnd);
            #pragma unroll
            for (int j = 0; j < 12; ++j) P[j] = take ? opr[cnd][j] : P[j];
        }
        combine12(P, M, opr[i]);
        // fp16x2 spill to lane-private LDS column (no barrier needed)
        #pragma unroll
        for (int s2 = 0; s2 < 6; ++s2)
            sbh[w][(i-1)*6 + s2][lane] = pkh(opr[i][2*s2], opr[i][2*s2+1]);
    }

    // ---- small outputs: direct vectorized stores ----
    {
        float2* d0 = reinterpret_cast<float2*>(dSC + (size_t)n * 14);
        #pragma unroll
        for (int k = 0; k < 7; ++k) d0[k] = make_float2(sc[2*k], sc[2*k+1]);
        float4* d1 = reinterpret_cast<float4*>(dBB + (size_t)n * 12);
        #pragma unroll
        for (int k = 0; k < 3; ++k) d1[k] = make_float4(bb[4*k], bb[4*k+1], bb[4*k+2], bb[4*k+3]);
        float4* d2 = reinterpret_cast<float4*>(dOprBB + (size_t)n * 12);
        #pragma unroll
        for (int k = 0; k < 3; ++k) d2[k] = make_float4(opr[0][4*k], opr[0][4*k+1], opr[0][4*k+2], opr[0][4*k+3]);
    }

    // ---- atoms: fp16 LDS gather (conflict-free lane column) + g==0 merge ----
    const float4* G4 = reinterpret_cast<const float4*>(sG + rt * 100);
    float* Rout = dR + (size_t)n * 72;
    #pragma unroll
    for (int c = 0; c < 3; ++c) {
        unsigned gw = (c == 0) ? gw0 : ((c == 1) ? gw1 : gw2);
        float rbuf[24];
        #pragma unroll
        for (int a4 = 0; a4 < 8; ++a4) {
            int a = c*8 + a4;
            int g = (int)((gw >> (a4*4)) & 7u);
            float4 gv = G4[a];
            int base = (g > 0) ? (g-1)*6 : 0;
            float O[12];
            #pragma unroll
            for (int s2 = 0; s2 < 6; ++s2) {
                unsigned u = sbh[w][base + s2][lane];
                O[2*s2]   = uplo(u);
                O[2*s2+1] = uphi(u);
            }
            bool g0 = (g == 0);
            #pragma unroll
            for (int j = 0; j < 12; ++j) O[j] = g0 ? opr[0][j] : O[j];
            rbuf[a4*3+0] = O[0]*gv.x + O[1]*gv.y + O[2]*gv.z + O[9];
            rbuf[a4*3+1] = O[3]*gv.x + O[4]*gv.y + O[5]*gv.z + O[10];
            rbuf[a4*3+2] = O[6]*gv.x + O[7]*gv.y + O[8]*gv.z + O[11];
        }
        float4* dst = reinterpret_cast<float4*>(Rout + c * 24);
        #pragma unroll
        for (int q = 0; q < 6; ++q)
            dst[q] = make_float4(rbuf[4*q], rbuf[4*q+1], rbuf[4*q+2], rbuf[4*q+3]);
    }
}

extern "C" void kernel_launch(void* const* d_in, const int* in_sizes, int n_in,
                              void* d_out, int out_size, void* d_ws, size_t ws_size,
                              hipStream_t stream) {
    const float* out0 = (const float*)d_in[0];
    const float* out1 = (const float*)d_in[1];
    const float* pos  = (const float*)d_in[2];
    const float* rT   = (const float*)d_in[3];
    const float* rG   = (const float*)d_in[4];
    const int*   res  = (const int*)d_in[5];
    const int*   td   = (const int*)d_in[6];
    const int*   gd   = (const int*)d_in[7];
    const int*   nr   = (const int*)d_in[8];

    int N = in_sizes[5];

    float* dR     = (float*)d_out;
    float* dOprBB = dR + (size_t)N * 72;
    float* dBB    = dOprBB + (size_t)N * 12;
    float* dSC    = dBB + (size_t)N * 12;

    dim3 grid((N + 255) / 256), block(256);
    hipLaunchKernelGGL(build_struct_kernel, grid, block, 0, stream,
                       out0, out1, pos, rT, rG, res, td, gd, nr,
                       dR, dOprBB, dBB, dSC, N);
}